// Round 16
// baseline (102.112 us; speedup 1.0000x reference)
//
#include <hip/hip_runtime.h>
#include <hip/hip_bf16.h>
#include <stdint.h>

// Problem constants
#define NB 8
#define NP 225      // patches per image
#define PGRID 15    // 15x15 patch grid
#define DH 256      // hidden
#define DIN 130     // per-node feature dim

typedef _Float16 f16x8 __attribute__((ext_vector_type(8)));   // 8 f16 = 4 VGPRs
typedef float    f32x4 __attribute__((ext_vector_type(4)));

static __device__ __forceinline__ float lrelu(float x) { return fmaxf(x, 0.01f * x); }

// ---------------------------------------------------------------------------
// K1 (fused prep): blocks 0..359 = pool+patch+U/V projection (f32 math, f16
// store) + accg zeroing; blocks 360..391 = W1 repack to fragment-linear f16.
__global__ void prep_kernel(const float* __restrict__ x, const float* __restrict__ W0,
                            const float* __restrict__ b0, const float* __restrict__ W1,
                            _Float16* __restrict__ U, _Float16* __restrict__ V,
                            _Float16* __restrict__ W1F, float* __restrict__ accg) {
    int blk = blockIdx.x;
    if (blk >= 360) {
        int t = (blk - 360) * 256 + threadIdx.x;   // 8192 threads = 128 slots * 64 lanes
        int slot = t >> 6, l = t & 63;
        int nf = slot >> 3, ks = slot & 7;
        int n = nf * 16 + (l & 15);
        int kb = l >> 4;
        f16x8 wv;
        #pragma unroll
        for (int e = 0; e < 8; ++e) {
            int k = ks * 32 + kb * 8 + e;
            wv[e] = (_Float16)W1[k * DH + n];
        }
        reinterpret_cast<f16x8*>(W1F)[t] = wv;
        return;
    }
    int bb = blk / 45;
    int p0 = (blk % 45) * 5;
    if (blk % 45 == 0) accg[bb * DH + threadIdx.x] = 0.0f;   // replaces memset
    __shared__ float fl[5][DIN];
    int t = threadIdx.x;
    for (int idx = t; idx < 5 * DIN; idx += 256) {
        int pp = idx / DIN, f = idx % DIN;
        int p = p0 + pp;
        int r = p / PGRID, c = p % PGRID;
        float val;
        if (f < 128) {
            int ch = f >> 2, q = f & 3, ki = q >> 1, kj = q & 1;
            int R = r + ki, C = c + kj;                 // pooled coords (0..15)
            const float* xp = x + (((size_t)bb * 32 + ch) * 32 + 2 * R) * 32 + 2 * C;
            val = 0.25f * (xp[0] + xp[1] + xp[32] + xp[33]);
        } else {
            val = (f == 128) ? (float)(c - 7) : (float)(r - 7);  // cx, cy
        }
        fl[pp][f] = val;
    }
    __syncthreads();
    int n = t;  // 0..255
    float u[5] = {0, 0, 0, 0, 0}, v[5] = {0, 0, 0, 0, 0};
    for (int k = 0; k < DIN; ++k) {
        float wa = W0[k * DH + n];
        float wb = W0[(DIN + k) * DH + n];
        #pragma unroll
        for (int pp = 0; pp < 5; ++pp) {
            float f = fl[pp][k];
            u[pp] = fmaf(f, wa, u[pp]);
            v[pp] = fmaf(f, wb, v[pp]);
        }
    }
    float bb0 = b0[n];
    #pragma unroll
    for (int pp = 0; pp < 5; ++pp) {
        size_t base = ((size_t)bb * NP + p0 + pp) * DH + n;
        U[base] = (_Float16)(u[pp] + bb0);  // fold b0 into U
        V[base] = (_Float16)v[pp];
    }
}

// ---------------------------------------------------------------------------
// K2: main relational GEMM + reduce — PRODUCER/CONSUMER wave specialization.
// R12's 5340 cyc/block-iter = MFMA 2483 + LDS 2690 SERIAL: barriers bunch all
// waves into the same phase. R7/R15 showed phase-split (dbuf) spills because
// acc must cross a barrier. Role-split avoids both: 512-thread block,
//   waves 0-3 (producers): build A(tile t+1) into Af[cur^1] — U from LDS,
//     V from L2 global (producers tolerate latency; ~800 cyc < MFMA window),
//   waves 4-7 (consumers): persistent bv (128 regs, N=64 slice), 32 A-reads +
//     128 MFMA + epilogue per iter from Af[cur].
// HW puts wave w on SIMD w&3 -> each SIMD = 1 producer + 1 consumer, so MFMA
// issues continuously while build runs (m114). ONE barrier per iter (covers
// "consumers done reading cur" + "producers done writing cur^1"). acc never
// crosses a barrier. Consumer regs ~210 < 256 cap of (512,2).
// LDS: 2x32KB Af + 8.25KB Upad = 72.25KB -> 1 block/CU; grid 240 (all resident).
__global__ __launch_bounds__(512, 2) void main_kernel(
        const _Float16* __restrict__ U, const _Float16* __restrict__ V,
        const _Float16* __restrict__ W1F, const float* __restrict__ b1,
        float* __restrict__ accg) {
    __shared__ f16x8 Af[2][2048];         // 2 x 32 KB: [mf(4)][ks(8)][lane(64)]
    __shared__ _Float16 Upad[16 * 264];   // 8.25 KB
    const int JT = 15, CHUNKS = 2;        // chunk0: tiles 0..28, chunk1: 29..56
    int blk = blockIdx.x;
    int bb = blk / (JT * CHUNKS);
    int rem = blk % (JT * CHUNKS);
    int jt = rem / CHUNKS, ch = rem % CHUNKS;
    int j0 = jt * 16;
    int tile0 = ch * 29;
    int nt = ch ? 28 : 29;
    int t = threadIdx.x, l = t & 63, w = t >> 6;
    bool producer = (w < 4);
    int pw = w & 3;                       // producer: mf owned; consumer: nf-group

    // ---- stage U tile (512 threads x 8 f16 = 16x256 exactly)
    {
        int jj = t >> 5, kk = (t & 31) * 8;
        int jc = j0 + jj; if (jc >= NP) jc = NP - 1;
        *reinterpret_cast<f16x8*>(&Upad[jj * 264 + kk]) =
            *reinterpret_cast<const f16x8*>(U + ((size_t)bb * NP + jc) * DH + kk);
    }

    int kb = l >> 4;
    const _Float16* Urow = &Upad[(l & 15) * 264 + kb * 8];
    const _Float16* Vbb = V + (size_t)bb * NP * DH;

    // ---- consumer-persistent state (allocated per-kernel; producers ignore)
    f16x8 bv[4][8];
    float b1v[4] = {0, 0, 0, 0};
    float jmask[4] = {0, 0, 0, 0};
    float psum[4] = {0.f, 0.f, 0.f, 0.f};
    if (!producer) {
        const f16x8* Bp = reinterpret_cast<const f16x8*>(W1F);
        #pragma unroll
        for (int nf = 0; nf < 4; ++nf)
            #pragma unroll
            for (int ks = 0; ks < 8; ++ks)
                bv[nf][ks] = Bp[((pw * 4 + nf) * 8 + ks) * 64 + l];
        #pragma unroll
        for (int nf = 0; nf < 4; ++nf) b1v[nf] = b1[pw * 64 + nf * 16 + (l & 15)];
        int rowg = l >> 4;
        #pragma unroll
        for (int r = 0; r < 4; ++r) jmask[r] = (j0 + rowg * 4 + r) < NP ? 1.0f : 0.0f;
    }
    __syncthreads();   // Upad visible

    // producer: build A for i-tile itl2 into Af[bufi]; wave pw owns mf=pw.
    auto build = [&](int itl2, int bufi) {
        int ic = (tile0 + itl2) * 4 + pw; if (ic >= NP) ic = NP - 1;
        const _Float16* Vr = Vbb + (size_t)ic * DH + kb * 8;
        #pragma unroll
        for (int ks = 0; ks < 8; ++ks) {
            f16x8 uv = *reinterpret_cast<const f16x8*>(Urow + ks * 32);
            f16x8 vv = *reinterpret_cast<const f16x8*>(Vr + ks * 32);  // L2
            f16x8 s  = uv + vv;
            f16x8 a  = __builtin_elementwise_max(s, s * (_Float16)0.01f);
            Af[bufi][(pw * 8 + ks) * 64 + l] = a;
        }
    };

    if (producer) build(0, 0);
    __syncthreads();
    int cur = 0;

    for (int itl = 0; itl < nt; ++itl) {
        if (producer) {
            if (itl + 1 < nt) build(itl + 1, cur ^ 1);
        } else {
            int i0 = (tile0 + itl) * 4;
            f32x4 acc[4][4];
            #pragma unroll
            for (int mf = 0; mf < 4; ++mf)
                #pragma unroll
                for (int nf = 0; nf < 4; ++nf)
                    acc[mf][nf] = (f32x4){b1v[nf], b1v[nf], b1v[nf], b1v[nf]};
            #pragma unroll
            for (int ks = 0; ks < 8; ++ks) {
                f16x8 av[4];
                #pragma unroll
                for (int mf = 0; mf < 4; ++mf)
                    av[mf] = Af[cur][(mf * 8 + ks) * 64 + l];
                #pragma unroll
                for (int mf = 0; mf < 4; ++mf)
                    #pragma unroll
                    for (int nf = 0; nf < 4; ++nf)
                        acc[mf][nf] = __builtin_amdgcn_mfma_f32_16x16x32_f16(
                            av[mf], bv[nf][ks], acc[mf][nf], 0, 0, 0);
            }
            // epilogue: lrelu + jmask-fma row-sum (wave-uniform mf skip)
            #pragma unroll
            for (int mf = 0; mf < 4; ++mf) {
                if (i0 + mf < NP) {
                    #pragma unroll
                    for (int r = 0; r < 4; ++r) {
                        #pragma unroll
                        for (int nf = 0; nf < 4; ++nf) {
                            float a = acc[mf][nf][r];
                            float h = fmaxf(a, 0.01f * a);
                            psum[nf] = fmaf(h, jmask[r], psum[nf]);
                        }
                    }
                }
            }
        }
        __syncthreads();   // consumers done reading cur; producers done writing cur^1
        cur ^= 1;
    }

    // ---- consumer block-level reduce + one atomicAdd set
    if (!producer) {
        #pragma unroll
        for (int nf = 0; nf < 4; ++nf) {
            psum[nf] += __shfl_xor(psum[nf], 16);
            psum[nf] += __shfl_xor(psum[nf], 32);
        }
        if (l < 16) {
            #pragma unroll
            for (int nf = 0; nf < 4; ++nf)
                atomicAdd(&accg[bb * DH + pw * 64 + nf * 16 + l], psum[nf]);
        }
    }
}

// ---------------------------------------------------------------------------
// K3: out[b,o] = (accg[b,:]/P^2) @ Wout + bout
__global__ void out_kernel(const float* __restrict__ accg, const float* __restrict__ Wout,
                           const float* __restrict__ bout, float* __restrict__ out) {
    int bb = blockIdx.x;
    int o = threadIdx.x;  // 0..127
    float s = 0.f;
    for (int n = 0; n < DH; ++n)
        s = fmaf(accg[bb * DH + n], Wout[n * 128 + o], s);
    out[bb * 128 + o] = s * (1.0f / 50625.0f) + bout[o];
}

// ---------------------------------------------------------------------------
extern "C" void kernel_launch(void* const* d_in, const int* in_sizes, int n_in,
                              void* d_out, int out_size, void* d_ws, size_t ws_size,
                              hipStream_t stream) {
    const float* x    = (const float*)d_in[0];
    const float* W0   = (const float*)d_in[1];
    const float* b0   = (const float*)d_in[2];
    const float* W1   = (const float*)d_in[3];
    const float* b1   = (const float*)d_in[4];
    const float* Wout = (const float*)d_in[5];
    const float* bout = (const float*)d_in[6];
    float* out = (float*)d_out;

    char* ws = (char*)d_ws;
    _Float16* U    = (_Float16*)(ws);                      // 8*225*256*2 =   921,600 B
    _Float16* V    = (_Float16*)(ws + 921600);             //                 921,600 B
    _Float16* W1F  = (_Float16*)(ws + 2 * 921600);         // 256*256*2  =   131,072 B
    float*    accg = (float*)(ws + 2 * 921600 + 131072);   // 8*256*4    =     8,192 B

    prep_kernel<<<392, 256, 0, stream>>>(x, W0, b0, W1, U, V, W1F, accg);
    main_kernel<<<NB * 15 * 2, 512, 0, stream>>>(U, V, W1F, b1, accg);
    out_kernel<<<NB, 128, 0, stream>>>(accg, Wout, bout, out);
}